// Round 9
// baseline (410.145 us; speedup 1.0000x reference)
//
#include <hip/hip_runtime.h>
#include <hip/hip_bf16.h>

#define Bb 128
#define Tt 1024
#define Nn 128
#define Ss 256
#define NEGF (-1e30f)
#define D9 9.0f   // fixed log-domain shift per active step (absorbed via c at the end)

typedef __attribute__((ext_vector_type(8))) short short8;  // 8 bf16 (4 VGPRs) — MFMA A/B frag
typedef __attribute__((ext_vector_type(4))) float f32x4;   // MFMA C/D frag

__device__ __forceinline__ short bf16b(float f) {
    __hip_bfloat16 h = __float2bfloat16(f);
    return *reinterpret_cast<short*>(&h);
}

// Single-instruction packed f32->bf16 (RNE).
__device__ __forceinline__ unsigned int cvt_pk_bf16(float lo, float hi) {
    unsigned int r;
    asm("v_cvt_pk_bf16_f32 %0, %1, %2" : "=v"(r) : "v"(lo), "v"(hi));
    return r;
}

// Raw workgroup barrier draining ONLY LDS (lgkmcnt), not vmcnt: the register
// ring prefetch loads stay in flight across the barrier.
#define LDS_BARRIER() asm volatile("s_waitcnt lgkmcnt(0)\n\ts_barrier" ::: "memory")

// ---- FCC per-step body: 4-wave M-split + PERMUTED-STATE own-chunk bypass,
// INLINE-EXP variant (round 9). The Wm precompute pipeline (exp_w dispatch +
// 128MB HBM round-trip) is removed: each wave loads its 8 x-floats directly
// (2 loads/step -> 16 rows x 2 lines = 64 lines/step/wave, 8x below round-1's
// TA-bound geometry; x is L3-resident) and applies exp(x-9) inline (16 v_exp,
// issued in MFMA-latency gaps). Step floor is unchanged: 8 MFMA x ~40cy
// wave-issue-block + read latency + tail + barrier (~650cy, rounds 4/6).
#define FCC_STEP(t_, k_)                                                       \
    {                                                                          \
        const int t = (t_);                                                    \
        const int sl  = (k_) & 3;        /* compile-time ring slot */          \
        const int RPp = ((k_) & 1) ^ 1;  /* read parity  = (t-1)&1 */          \
        const int WPp = (k_) & 1;        /* write parity = t&1 */              \
        short8 bfA = *(const short8*)(rp[RPp][0]);                             \
        short8 bfB = *(const short8*)(rp[RPp][1]);                             \
        short8 bfC = *(const short8*)(rp[RPp][2]);                             \
        const f32x4 zz = {0.f, 0.f, 0.f, 0.f};                                 \
        /* own-chunk MFMAs: no LDS dependency — fill the read-latency window */\
        f32x4 c1_0 = __builtin_amdgcn_mfma_f32_16x16x32_bf16(e_own0, bf_own, zz, 0, 0, 0); \
        f32x4 c1_1 = __builtin_amdgcn_mfma_f32_16x16x32_bf16(e_own1, bf_own, zz, 0, 0, 0); \
        f32x4 w0 = xs[sl][0], w1 = xs[sl][1];                                  \
        w0[0] = __expf(w0[0] - D9); w0[1] = __expf(w0[1] - D9);                \
        w0[2] = __expf(w0[2] - D9); w0[3] = __expf(w0[3] - D9);                \
        w1[0] = __expf(w1[0] - D9); w1[1] = __expf(w1[1] - D9);                \
        w1[2] = __expf(w1[2] - D9); w1[3] = __expf(w1[3] - D9);                \
        { /* refill ring slot sl with x-row t+4 (first use 4 steps away) */    \
            int tn = t + 4; if (tn > Tt - 1) tn = Tt - 1;                      \
            const float* gb = wbase + (size_t)tn * Nn;                         \
            xs[sl][0] = *(const f32x4*)(gb);                                   \
            xs[sl][1] = *(const f32x4*)(gb + 4);                               \
        }                                                                      \
        if ((k_) == 0) { /* renorm apply: wred written at k==7, post-barrier */\
            float m = fmaxf(fmaxf(wred[0][g], wred[1][g]),                     \
                            fmaxf(wred[2][g], wred[3][g]));                    \
            float invm = 1.0f / m;                                             \
            c += __logf(m);                                                    \
            w0 *= invm; w1 *= invm;                                            \
        }                                                                      \
        c1_0 = __builtin_amdgcn_mfma_f32_16x16x32_bf16(eoA0, bfA, c1_0, 0, 0, 0); \
        c1_1 = __builtin_amdgcn_mfma_f32_16x16x32_bf16(eoA1, bfA, c1_1, 0, 0, 0); \
        f32x4 c2_0 = __builtin_amdgcn_mfma_f32_16x16x32_bf16(eoB0, bfB, zz, 0, 0, 0); \
        f32x4 c2_1 = __builtin_amdgcn_mfma_f32_16x16x32_bf16(eoB1, bfB, zz, 0, 0, 0); \
        c2_0 = __builtin_amdgcn_mfma_f32_16x16x32_bf16(eoC0, bfC, c2_0, 0, 0, 0); \
        c2_1 = __builtin_amdgcn_mfma_f32_16x16x32_bf16(eoC1, bfC, c2_1, 0, 0, 0); \
        f32x4 un0 = w0 * (c1_0 + c2_0);                                        \
        f32x4 un1 = w1 * (c1_1 + c2_1);                                        \
        if (t == len - 1) { /* snapshot: 4 quad-lanes of a column share len */ \
            float s = (un0[0] + un0[1]) + (un0[2] + un0[3])                    \
                    + (un1[0] + un1[1]) + (un1[2] + un1[3]);                   \
            s += __shfl_xor(s, 16);                                            \
            s += __shfl_xor(s, 32);                                            \
            sfin = s; cfin = c;                                                \
        }                                                                      \
        {                                                                      \
            union { short8 s8; unsigned u[4]; } OW;                            \
            OW.u[0] = cvt_pk_bf16(un0[0], un0[1]);                             \
            OW.u[1] = cvt_pk_bf16(un0[2], un0[3]);                             \
            OW.u[2] = cvt_pk_bf16(un1[0], un1[1]);                             \
            OW.u[3] = cvt_pk_bf16(un1[2], un1[3]);                             \
            *reinterpret_cast<short8*>(wptr[WPp]) = OW.s8;  /* 1x b128 */      \
            bf_own = OW.s8;   /* own-chunk B-frag for NEXT step, in regs */    \
        }                                                                      \
        if ((k_) == 7) { /* renorm measure (unconditional; garbage harmless) */\
            float mm = fmaxf(fmaxf(un0[0], un0[1]), fmaxf(un0[2], un0[3]));    \
            mm = fmaxf(mm, fmaxf(fmaxf(un1[0], un1[1]), fmaxf(un1[2], un1[3])));\
            mm = fmaxf(mm, __shfl_xor(mm, 16));                                \
            mm = fmaxf(mm, __shfl_xor(mm, 32));                                \
            if (lane < 16) wred[q][lane] = mm;                                 \
        }                                                                      \
        LDS_BARRIER();                                                         \
    }

// ---- FAC per-step body (unchanged).
#define FAC_STEP(t_, k_)                                                       \
    {                                                                          \
        const int t = (t_);                                                    \
        const int d = ((k_) + 7) & 7;                                          \
        float e0 = em[d][0], e1 = em[d][1], e2 = em[d][2], e3 = em[d][3];      \
        int tn = t + 8; if (tn > Tt - 1) tn = Tt - 1;                          \
        const float* xrow = xb + (size_t)tn * Nn;                              \
        em[d][0] = xrow[tgi[0]]; em[d][1] = xrow[tgi[1]];                      \
        em[d][2] = xrow[tgi[2]]; em[d][3] = xrow[tgi[3]];                      \
        float bup = __shfl_up(bt[3], 1);                                       \
        float prev0 = (lane == 0) ? NEGF : bup;                                \
        float nb[4];                                                           \
        {                                                                      \
            float aa = bt[0] + st[0], bb = prev0 + ntr[0];                     \
            float hi = fmaxf(aa, bb), lo = fminf(aa, bb);                      \
            nb[0] = e0 + hi + __logf(1.0f + __expf(lo - hi));                  \
        }                                                                      \
        {                                                                      \
            float aa = bt[1] + st[1], bb = bt[0] + ntr[1];                     \
            float hi = fmaxf(aa, bb), lo = fminf(aa, bb);                      \
            nb[1] = e1 + hi + __logf(1.0f + __expf(lo - hi));                  \
        }                                                                      \
        {                                                                      \
            float aa = bt[2] + st[2], bb = bt[1] + ntr[2];                     \
            float hi = fmaxf(aa, bb), lo = fminf(aa, bb);                      \
            nb[2] = e2 + hi + __logf(1.0f + __expf(lo - hi));                  \
        }                                                                      \
        {                                                                      \
            float aa = bt[3] + st[3], bb = bt[2] + ntr[3];                     \
            float hi = fmaxf(aa, bb), lo = fminf(aa, bb);                      \
            nb[3] = e3 + hi + __logf(1.0f + __expf(lo - hi));                  \
        }                                                                      \
        if (t < len) {                                                         \
            bt[0] = nb[0]; bt[1] = nb[1]; bt[2] = nb[2]; bt[3] = nb[3];        \
        }                                                                      \
    }

// blocks 0..7:  FCC, 16 batches each, 4 waves M-split over (permuted) states
// blocks 8..39: FAC, 4 batches each (1 wave per batch, wave-synchronous)
__global__ __launch_bounds__(256, 1) void asg_main(
    const float* __restrict__ trans, const float* __restrict__ x,
    const int* __restrict__ targets, const int* __restrict__ ilen,
    const int* __restrict__ tlen,
    float* __restrict__ fcc_out, float* __restrict__ fac_out)
{
    __shared__ __align__(16) short ut[2][16][136];  // pad 8: 272B row
    __shared__ float wred[4][16];

    const int tid  = threadIdx.x;
    const int q    = tid >> 6;
    const int lane = tid & 63;

    if (blockIdx.x < 8) {
        // ========== FCC (4-wave M-split, permuted-state own-chunk bypass) =====
        const int g    = lane & 15;     // batch column
        const int quad = lane >> 4;
        const int wv   = blockIdx.x;
        const int b    = (wv << 4) + g;
        const int len  = ilen[b];

        // Direct x base for this lane's 8 states: floats 32q+8quad .. +7 of
        // batch b's row. Per load instr: 16 rows x 2 lines = 32 lines (L3-hot).
        const float* wbase = x + (size_t)b * (Tt * Nn) + 32 * q + 8 * quad;

        // E A-frags with the sigma row permutation:
        //   ea[mt][kc]: A row m=g -> trans row 32q + 8*(g>>2) + 4*mt + (g&3),
        //   k-cols: 32*kc + 8*quad + jj  (standard state order on K).
        short8 ea[2][4];
        #pragma unroll
        for (int mt = 0; mt < 2; ++mt) {
            const int srow = 32 * q + 8 * (g >> 2) + 4 * mt + (g & 3);
            const float* tr = trans + (size_t)srow * Nn + quad * 8;
            #pragma unroll
            for (int kc = 0; kc < 4; ++kc) {
                short8 v;
                #pragma unroll
                for (int jj = 0; jj < 8; ++jj)
                    v[jj] = bf16b(__expf(tr[kc * 32 + jj]));
                ea[mt][kc] = v;
            }
        }

        // One-shot wave-uniform selection (all loop-body indices static):
        // own chunk kc==q stays in registers; the other three are LDS reads.
        short8 e_own0, e_own1, eoA0, eoA1, eoB0, eoB1, eoC0, eoC1;
        int oc0, oc1, oc2;   // short offsets of the 3 non-own chunks
        if (q == 0) {
            e_own0 = ea[0][0]; e_own1 = ea[1][0];
            eoA0 = ea[0][1]; eoA1 = ea[1][1];
            eoB0 = ea[0][2]; eoB1 = ea[1][2];
            eoC0 = ea[0][3]; eoC1 = ea[1][3];
            oc0 = 32; oc1 = 64; oc2 = 96;
        } else if (q == 1) {
            e_own0 = ea[0][1]; e_own1 = ea[1][1];
            eoA0 = ea[0][0]; eoA1 = ea[1][0];
            eoB0 = ea[0][2]; eoB1 = ea[1][2];
            eoC0 = ea[0][3]; eoC1 = ea[1][3];
            oc0 = 0; oc1 = 64; oc2 = 96;
        } else if (q == 2) {
            e_own0 = ea[0][2]; e_own1 = ea[1][2];
            eoA0 = ea[0][0]; eoA1 = ea[1][0];
            eoB0 = ea[0][1]; eoB1 = ea[1][1];
            eoC0 = ea[0][3]; eoC1 = ea[1][3];
            oc0 = 0; oc1 = 32; oc2 = 96;
        } else {
            e_own0 = ea[0][3]; e_own1 = ea[1][3];
            eoA0 = ea[0][0]; eoA1 = ea[1][0];
            eoB0 = ea[0][1]; eoB1 = ea[1][1];
            eoC0 = ea[0][2]; eoC1 = ea[1][2];
            oc0 = 0; oc1 = 32; oc2 = 64;
        }

        // Precomputed LDS pointers (static [parity][i] indexing in the loop).
        const short* rp[2][3];
        short* wptr[2];
        {
            const short* b0 = &ut[0][g][8 * quad];
            const short* b1 = &ut[1][g][8 * quad];
            rp[0][0] = b0 + oc0; rp[0][1] = b0 + oc1; rp[0][2] = b0 + oc2;
            rp[1][0] = b1 + oc0; rp[1][1] = b1 + oc1; rp[1][2] = b1 + oc2;
            wptr[0] = &ut[0][g][32 * q + 8 * quad];
            wptr[1] = &ut[1][g][32 * q + 8 * quad];
        }

        f32x4 xs[4][2];   // x ring, depth 4 (static indices only)
        short8 bf_own;    // own-chunk B-frag for the next step (pure registers)
        float c = 0.f, sfin = 1.0f, cfin = 0.f;

        {   // t = 0: u0 = exp(x0 - 9) -> LDS (bf16, 1x b128) + bf_own regs
            f32x4 v0 = *(const f32x4*)(wbase);
            f32x4 v1 = *(const f32x4*)(wbase + 4);
            v0[0]=__expf(v0[0]-D9); v0[1]=__expf(v0[1]-D9);
            v0[2]=__expf(v0[2]-D9); v0[3]=__expf(v0[3]-D9);
            v1[0]=__expf(v1[0]-D9); v1[1]=__expf(v1[1]-D9);
            v1[2]=__expf(v1[2]-D9); v1[3]=__expf(v1[3]-D9);
            union { short8 s8; unsigned u[4]; } OW;
            OW.u[0] = cvt_pk_bf16(v0[0], v0[1]);
            OW.u[1] = cvt_pk_bf16(v0[2], v0[3]);
            OW.u[2] = cvt_pk_bf16(v1[0], v1[1]);
            OW.u[3] = cvt_pk_bf16(v1[2], v1[3]);
            *reinterpret_cast<short8*>(wptr[0]) = OW.s8;
            bf_own = OW.s8;
        }
        // preload ring rows 1..4 into slots 1,2,3,0
        #pragma unroll
        for (int k = 1; k <= 4; ++k) {
            const float* rr = wbase + (size_t)k * Nn;
            xs[k & 3][0] = *(const f32x4*)(rr);
            xs[k & 3][1] = *(const f32x4*)(rr + 4);
        }
        __syncthreads();   // setup barrier (once; full drain acceptable)

        // steps t = 1..7, then 127 chunks of 8 (t = 8..1023)
        #pragma unroll
        for (int k = 1; k < 8; ++k) FCC_STEP(k, k)
        for (int tb = 8; tb < Tt; tb += 8) {
            #pragma unroll
            for (int k = 0; k < 8; ++k) FCC_STEP(tb + k, k)
        }

        // cross-wave sum of the snapshotted partials
        if (lane < 16) wred[q][lane] = sfin;
        __syncthreads();
        if (q == 0 && lane < 16) {
            float tot = wred[0][lane] + wred[1][lane] + wred[2][lane] + wred[3][lane];
            fcc_out[(wv << 4) + lane] = cfin + D9 * (float)len + __logf(tot);
        }
    } else {
        // ================= FAC (1 wave per batch, no barriers) =================
        const int b   = ((blockIdx.x - 8) << 2) + q;
        const int len = ilen[b];
        const int tl  = tlen[b];
        const float* xb = x + (size_t)b * Tt * Nn;

        int   tgi[4];
        float st[4], ntr[4], bt[4];
        #pragma unroll
        for (int r = 0; r < 4; ++r) {
            const int s = (lane << 2) + r;
            const int tgv = targets[b * Ss + s];
            const int pg  = (s == 0) ? tgv : targets[b * Ss + s - 1];
            tgi[r] = tgv;
            st[r]  = trans[tgv * Nn + tgv];
            ntr[r] = trans[tgv * Nn + pg];
            bt[r]  = (s == 0) ? xb[tgv] : NEGF;
        }
        // em ring depth 8; em[(k-1)&7] = x[k] for k=1..8 (constant indices)
        float em[8][4];
        #pragma unroll
        for (int k = 1; k <= 8; ++k) {
            int tt = k; if (tt > Tt - 1) tt = Tt - 1;
            const float* xrow = xb + (size_t)tt * Nn;
            em[(k - 1) & 7][0] = xrow[tgi[0]];
            em[(k - 1) & 7][1] = xrow[tgi[1]];
            em[(k - 1) & 7][2] = xrow[tgi[2]];
            em[(k - 1) & 7][3] = xrow[tgi[3]];
        }

        #pragma unroll
        for (int k = 1; k < 8; ++k) FAC_STEP(k, k)
        for (int tb = 8; tb < Tt; tb += 8) {
            #pragma unroll
            for (int k = 0; k < 8; ++k) FAC_STEP(tb + k, k)
        }

        #pragma unroll
        for (int r = 0; r < 4; ++r)
            if ((lane << 2) + r == tl - 1) fac_out[b] = bt[r];
    }
}

__global__ __launch_bounds__(128) void reduce_kernel(const float* __restrict__ fcc,
                                                     const float* __restrict__ fac,
                                                     float* __restrict__ out) {
    __shared__ float r2[2];
    int tid = threadIdx.x;
    float v = fcc[tid] - fac[tid];
    #pragma unroll
    for (int o = 32; o > 0; o >>= 1) v += __shfl_xor(v, o);
    if ((tid & 63) == 0) r2[tid >> 6] = v;
    __syncthreads();
    if (tid == 0) out[0] = (r2[0] + r2[1]) * (1.0f / Bb);
}

extern "C" void kernel_launch(void* const* d_in, const int* in_sizes, int n_in,
                              void* d_out, int out_size, void* d_ws, size_t ws_size,
                              hipStream_t stream) {
    const float* trans   = (const float*)d_in[0];
    const float* x       = (const float*)d_in[1];
    const int*   targets = (const int*)d_in[2];
    const int*   ilen    = (const int*)d_in[3];
    const int*   tlen    = (const int*)d_in[4];
    float* out = (float*)d_out;

    float* fcc = (float*)d_ws;                       // B floats
    float* fac = fcc + Bb;                           // B floats

    asg_main<<<40, 256, 0, stream>>>(trans, x, targets, ilen, tlen, fcc, fac);
    reduce_kernel<<<1, 128, 0, stream>>>(fcc, fac, out);
}

// Round 10
// 369.224 us; speedup vs baseline: 1.1108x; 1.1108x over previous
//
#include <hip/hip_runtime.h>
#include <hip/hip_bf16.h>

#define Bb 128
#define Tt 1024
#define Nn 128
#define Ss 256
#define NEGF (-1e30f)
#define D9 9.0f   // fixed log-domain shift per active step (absorbed via c at the end)

typedef __attribute__((ext_vector_type(8))) short short8;  // 8 bf16 (4 VGPRs) — MFMA A/B frag
typedef __attribute__((ext_vector_type(4))) float f32x4;   // MFMA C/D frag

__device__ __forceinline__ short bf16b(float f) {
    __hip_bfloat16 h = __float2bfloat16(f);
    return *reinterpret_cast<short*>(&h);
}

// Single-instruction packed f32->bf16 (RNE).
__device__ __forceinline__ unsigned int cvt_pk_bf16(float lo, float hi) {
    unsigned int r;
    asm("v_cvt_pk_bf16_f32 %0, %1, %2" : "=v"(r) : "v"(lo), "v"(hi));
    return r;
}

// Raw workgroup barrier draining ONLY LDS (lgkmcnt), not vmcnt: the register
// ring prefetch loads stay in flight across the barrier.
#define LDS_BARRIER() asm volatile("s_waitcnt lgkmcnt(0)\n\ts_barrier" ::: "memory")

// ---- FCC per-step body: 4-wave M-split + PERMUTED-STATE own-chunk bypass.
// (Round-8 best-verified structure. Step ~= read-latency + dependent MFMA
// chain + 16 DS ops on the shared LDS pipe + barrier ~= 623cy — the serial
// recurrence floor of this decomposition; 2-wave/8-wave splits model worse.)
#define FCC_STEP(t_, k_)                                                       \
    {                                                                          \
        const int t = (t_);                                                    \
        const int sl  = (k_) & 3;        /* compile-time ring slot */          \
        const int RPp = ((k_) & 1) ^ 1;  /* read parity  = (t-1)&1 */          \
        const int WPp = (k_) & 1;        /* write parity = t&1 */              \
        short8 bfA = *(const short8*)(rp[RPp][0]);                             \
        short8 bfB = *(const short8*)(rp[RPp][1]);                             \
        short8 bfC = *(const short8*)(rp[RPp][2]);                             \
        const f32x4 zz = {0.f, 0.f, 0.f, 0.f};                                 \
        /* own-chunk MFMAs: no LDS dependency — fill the read-latency window */\
        f32x4 c1_0 = __builtin_amdgcn_mfma_f32_16x16x32_bf16(e_own0, bf_own, zz, 0, 0, 0); \
        f32x4 c1_1 = __builtin_amdgcn_mfma_f32_16x16x32_bf16(e_own1, bf_own, zz, 0, 0, 0); \
        f32x4 w0 = xs[sl][0], w1 = xs[sl][1];                                  \
        if (!PRE) {                                                            \
            w0[0] = __expf(w0[0] - D9); w0[1] = __expf(w0[1] - D9);            \
            w0[2] = __expf(w0[2] - D9); w0[3] = __expf(w0[3] - D9);            \
            w1[0] = __expf(w1[0] - D9); w1[1] = __expf(w1[1] - D9);            \
            w1[2] = __expf(w1[2] - D9); w1[3] = __expf(w1[3] - D9);            \
        }                                                                      \
        { /* refill ring slot sl with w-row t+4 (first use 4 steps away) */    \
            int tn = t + 4; if (tn > Tt - 1) tn = Tt - 1;                      \
            const float* gb = wbase + (size_t)tn * TSTR;                       \
            xs[sl][0] = *(const f32x4*)(gb);                                   \
            xs[sl][1] = *(const f32x4*)(gb + MSTR);                            \
        }                                                                      \
        if ((k_) == 0) { /* renorm apply: wred written at k==7, post-barrier */\
            float m = fmaxf(fmaxf(wred[0][g], wred[1][g]),                     \
                            fmaxf(wred[2][g], wred[3][g]));                    \
            float invm = 1.0f / m;                                             \
            c += __logf(m);                                                    \
            w0 *= invm; w1 *= invm;                                            \
        }                                                                      \
        c1_0 = __builtin_amdgcn_mfma_f32_16x16x32_bf16(eoA0, bfA, c1_0, 0, 0, 0); \
        c1_1 = __builtin_amdgcn_mfma_f32_16x16x32_bf16(eoA1, bfA, c1_1, 0, 0, 0); \
        f32x4 c2_0 = __builtin_amdgcn_mfma_f32_16x16x32_bf16(eoB0, bfB, zz, 0, 0, 0); \
        f32x4 c2_1 = __builtin_amdgcn_mfma_f32_16x16x32_bf16(eoB1, bfB, zz, 0, 0, 0); \
        c2_0 = __builtin_amdgcn_mfma_f32_16x16x32_bf16(eoC0, bfC, c2_0, 0, 0, 0); \
        c2_1 = __builtin_amdgcn_mfma_f32_16x16x32_bf16(eoC1, bfC, c2_1, 0, 0, 0); \
        f32x4 un0 = w0 * (c1_0 + c2_0);                                        \
        f32x4 un1 = w1 * (c1_1 + c2_1);                                        \
        if (t == len - 1) { /* snapshot: 4 quad-lanes of a column share len */ \
            float s = (un0[0] + un0[1]) + (un0[2] + un0[3])                    \
                    + (un1[0] + un1[1]) + (un1[2] + un1[3]);                   \
            s += __shfl_xor(s, 16);                                            \
            s += __shfl_xor(s, 32);                                            \
            sfin = s; cfin = c;                                                \
        }                                                                      \
        {                                                                      \
            union { short8 s8; unsigned u[4]; } OW;                            \
            OW.u[0] = cvt_pk_bf16(un0[0], un0[1]);                             \
            OW.u[1] = cvt_pk_bf16(un0[2], un0[3]);                             \
            OW.u[2] = cvt_pk_bf16(un1[0], un1[1]);                             \
            OW.u[3] = cvt_pk_bf16(un1[2], un1[3]);                             \
            *reinterpret_cast<short8*>(wptr[WPp]) = OW.s8;  /* 1x b128 */      \
            bf_own = OW.s8;   /* own-chunk B-frag for NEXT step, in regs */    \
        }                                                                      \
        if ((k_) == 7) { /* renorm measure (unconditional; garbage harmless) */\
            float mm = fmaxf(fmaxf(un0[0], un0[1]), fmaxf(un0[2], un0[3]));    \
            mm = fmaxf(mm, fmaxf(fmaxf(un1[0], un1[1]), fmaxf(un1[2], un1[3])));\
            mm = fmaxf(mm, __shfl_xor(mm, 16));                                \
            mm = fmaxf(mm, __shfl_xor(mm, 32));                                \
            if (lane < 16) wred[q][lane] = mm;                                 \
        }                                                                      \
        LDS_BARRIER();                                                         \
    }

// ---- FAC per-step body (unchanged).
#define FAC_STEP(t_, k_)                                                       \
    {                                                                          \
        const int t = (t_);                                                    \
        const int d = ((k_) + 7) & 7;                                          \
        float e0 = em[d][0], e1 = em[d][1], e2 = em[d][2], e3 = em[d][3];      \
        int tn = t + 8; if (tn > Tt - 1) tn = Tt - 1;                          \
        const float* xrow = xb + (size_t)tn * Nn;                              \
        em[d][0] = xrow[tgi[0]]; em[d][1] = xrow[tgi[1]];                      \
        em[d][2] = xrow[tgi[2]]; em[d][3] = xrow[tgi[3]];                      \
        float bup = __shfl_up(bt[3], 1);                                       \
        float prev0 = (lane == 0) ? NEGF : bup;                                \
        float nb[4];                                                           \
        {                                                                      \
            float aa = bt[0] + st[0], bb = prev0 + ntr[0];                     \
            float hi = fmaxf(aa, bb), lo = fminf(aa, bb);                      \
            nb[0] = e0 + hi + __logf(1.0f + __expf(lo - hi));                  \
        }                                                                      \
        {                                                                      \
            float aa = bt[1] + st[1], bb = bt[0] + ntr[1];                     \
            float hi = fmaxf(aa, bb), lo = fminf(aa, bb);                      \
            nb[1] = e1 + hi + __logf(1.0f + __expf(lo - hi));                  \
        }                                                                      \
        {                                                                      \
            float aa = bt[2] + st[2], bb = bt[1] + ntr[2];                     \
            float hi = fmaxf(aa, bb), lo = fminf(aa, bb);                      \
            nb[2] = e2 + hi + __logf(1.0f + __expf(lo - hi));                  \
        }                                                                      \
        {                                                                      \
            float aa = bt[3] + st[3], bb = bt[2] + ntr[3];                     \
            float hi = fmaxf(aa, bb), lo = fminf(aa, bb);                      \
            nb[3] = e3 + hi + __logf(1.0f + __expf(lo - hi));                  \
        }                                                                      \
        if (t < len) {                                                         \
            bt[0] = nb[0]; bt[1] = nb[1]; bt[2] = nb[2]; bt[3] = nb[3];        \
        }                                                                      \
    }

// exp_w: LDS-transpose so BOTH global sides are coalesced (~24us, HBM-bound).
// One block per (wv,t) slab: load 16 rows x[16wv+br][t][:] coalesced -> exp ->
// LDS, then write the 8KB Wm slab linearly.
// Layout (must match asg_main exactly):
//   Wm[(t*8+wv)*2048 + (2q+half)*256 + l*4 + r]
//     = exp(x[16wv+(l&15)][t][32q + 8*(l>>4) + 4*half + r] - 9)
__global__ __launch_bounds__(256) void exp_w_kernel(const float* __restrict__ x,
                                                    float* __restrict__ w) {
    __shared__ float xl[16][132];   // 16 batch-rows x 128 states (+4 pad)
    const int tid = threadIdx.x;
    const int wv  = blockIdx.x & 7;
    const int t   = blockIdx.x >> 3;

    #pragma unroll
    for (int p = 0; p < 2; ++p) {
        const int br = (tid >> 5) + 8 * p;          // 0..15
        const int c0 = (tid & 31) << 2;             // 0..124
        const float* src = x + ((size_t)((wv << 4) + br) * Tt + t) * Nn + c0;
        f32x4 v = *(const f32x4*)src;
        f32x4 r;
        r[0] = __expf(v[0] - D9); r[1] = __expf(v[1] - D9);
        r[2] = __expf(v[2] - D9); r[3] = __expf(v[3] - D9);
        *(f32x4*)&xl[br][c0] = r;
    }
    __syncthreads();

    f32x4* dst4 = (f32x4*)(w + (size_t)blockIdx.x * 2048);
    #pragma unroll
    for (int i = 0; i < 2; ++i) {
        const int lin = tid + 256 * i;              // f32x4 unit 0..511
        const int qh  = lin >> 6;                   // 2q+half, 0..7
        const int l   = lin & 63;
        const int j   = ((qh >> 1) << 5) + ((l >> 4) << 3) + ((qh & 1) << 2);
        dst4[lin] = *(const f32x4*)&xl[l & 15][j];
    }
}

// blocks 0..7:  FCC, 16 batches each, 4 waves M-split over (permuted) states
// blocks 8..39: FAC, 4 batches each (1 wave per batch, wave-synchronous)
template <bool PRE>
__global__ __launch_bounds__(256, 1) void asg_main(
    const float* __restrict__ trans, const float* __restrict__ x,
    const float* __restrict__ Wm,
    const int* __restrict__ targets, const int* __restrict__ ilen,
    const int* __restrict__ tlen,
    float* __restrict__ fcc_out, float* __restrict__ fac_out)
{
    __shared__ __align__(16) short ut[2][16][136];  // pad 8: 272B row
    __shared__ float wred[4][16];

    const int tid  = threadIdx.x;
    const int q    = tid >> 6;
    const int lane = tid & 63;

    if (blockIdx.x < 8) {
        // ========== FCC (4-wave M-split, permuted-state own-chunk bypass) =====
        const int g    = lane & 15;     // batch column
        const int quad = lane >> 4;
        const int wv   = blockIdx.x;
        const int b    = (wv << 4) + g;
        const int len  = ilen[b];

        constexpr int TSTR = PRE ? 16384 : Nn;   // floats per t-step in source
        constexpr int MSTR = PRE ? 256 : 4;      // floats between half 0 and 1
        const float* wbase = PRE
            ? (Wm + (size_t)((wv << 3) + (q << 1)) * 256 + (lane << 2))
            : (x + (size_t)b * (Tt * Nn) + 32 * q + 8 * quad);

        // E A-frags with the sigma row permutation:
        //   ea[mt][kc]: A row m=g -> trans row 32q + 8*(g>>2) + 4*mt + (g&3),
        //   k-cols: 32*kc + 8*quad + jj  (standard state order on K).
        short8 ea[2][4];
        #pragma unroll
        for (int mt = 0; mt < 2; ++mt) {
            const int srow = 32 * q + 8 * (g >> 2) + 4 * mt + (g & 3);
            const float* tr = trans + (size_t)srow * Nn + quad * 8;
            #pragma unroll
            for (int kc = 0; kc < 4; ++kc) {
                short8 v;
                #pragma unroll
                for (int jj = 0; jj < 8; ++jj)
                    v[jj] = bf16b(__expf(tr[kc * 32 + jj]));
                ea[mt][kc] = v;
            }
        }

        // One-shot wave-uniform selection (all loop-body indices static):
        // own chunk kc==q stays in registers; the other three are LDS reads.
        short8 e_own0, e_own1, eoA0, eoA1, eoB0, eoB1, eoC0, eoC1;
        int oc0, oc1, oc2;   // short offsets of the 3 non-own chunks
        if (q == 0) {
            e_own0 = ea[0][0]; e_own1 = ea[1][0];
            eoA0 = ea[0][1]; eoA1 = ea[1][1];
            eoB0 = ea[0][2]; eoB1 = ea[1][2];
            eoC0 = ea[0][3]; eoC1 = ea[1][3];
            oc0 = 32; oc1 = 64; oc2 = 96;
        } else if (q == 1) {
            e_own0 = ea[0][1]; e_own1 = ea[1][1];
            eoA0 = ea[0][0]; eoA1 = ea[1][0];
            eoB0 = ea[0][2]; eoB1 = ea[1][2];
            eoC0 = ea[0][3]; eoC1 = ea[1][3];
            oc0 = 0; oc1 = 64; oc2 = 96;
        } else if (q == 2) {
            e_own0 = ea[0][2]; e_own1 = ea[1][2];
            eoA0 = ea[0][0]; eoA1 = ea[1][0];
            eoB0 = ea[0][1]; eoB1 = ea[1][1];
            eoC0 = ea[0][3]; eoC1 = ea[1][3];
            oc0 = 0; oc1 = 32; oc2 = 96;
        } else {
            e_own0 = ea[0][3]; e_own1 = ea[1][3];
            eoA0 = ea[0][0]; eoA1 = ea[1][0];
            eoB0 = ea[0][1]; eoB1 = ea[1][1];
            eoC0 = ea[0][2]; eoC1 = ea[1][2];
            oc0 = 0; oc1 = 32; oc2 = 64;
        }

        // Precomputed LDS pointers (static [parity][i] indexing in the loop).
        const short* rp[2][3];
        short* wptr[2];
        {
            const short* b0 = &ut[0][g][8 * quad];
            const short* b1 = &ut[1][g][8 * quad];
            rp[0][0] = b0 + oc0; rp[0][1] = b0 + oc1; rp[0][2] = b0 + oc2;
            rp[1][0] = b1 + oc0; rp[1][1] = b1 + oc1; rp[1][2] = b1 + oc2;
            wptr[0] = &ut[0][g][32 * q + 8 * quad];
            wptr[1] = &ut[1][g][32 * q + 8 * quad];
        }

        f32x4 xs[4][2];   // w ring, depth 4 (static indices only)
        short8 bf_own;    // own-chunk B-frag for the next step (pure registers)
        float c = 0.f, sfin = 1.0f, cfin = 0.f;

        {   // t = 0: u0 = exp(x0 - 9) -> LDS (bf16, 1x b128) + bf_own regs
            f32x4 v0 = *(const f32x4*)(wbase);
            f32x4 v1 = *(const f32x4*)(wbase + MSTR);
            if (!PRE) {
                v0[0]=__expf(v0[0]-D9); v0[1]=__expf(v0[1]-D9);
                v0[2]=__expf(v0[2]-D9); v0[3]=__expf(v0[3]-D9);
                v1[0]=__expf(v1[0]-D9); v1[1]=__expf(v1[1]-D9);
                v1[2]=__expf(v1[2]-D9); v1[3]=__expf(v1[3]-D9);
            }
            union { short8 s8; unsigned u[4]; } OW;
            OW.u[0] = cvt_pk_bf16(v0[0], v0[1]);
            OW.u[1] = cvt_pk_bf16(v0[2], v0[3]);
            OW.u[2] = cvt_pk_bf16(v1[0], v1[1]);
            OW.u[3] = cvt_pk_bf16(v1[2], v1[3]);
            *reinterpret_cast<short8*>(wptr[0]) = OW.s8;
            bf_own = OW.s8;
        }
        // preload ring rows 1..4 into slots 1,2,3,0
        #pragma unroll
        for (int k = 1; k <= 4; ++k) {
            const float* rr = wbase + (size_t)k * TSTR;
            xs[k & 3][0] = *(const f32x4*)(rr);
            xs[k & 3][1] = *(const f32x4*)(rr + MSTR);
        }
        __syncthreads();   // setup barrier (once; full drain acceptable)

        // steps t = 1..7, then 127 chunks of 8 (t = 8..1023)
        #pragma unroll
        for (int k = 1; k < 8; ++k) FCC_STEP(k, k)
        for (int tb = 8; tb < Tt; tb += 8) {
            #pragma unroll
            for (int k = 0; k < 8; ++k) FCC_STEP(tb + k, k)
        }

        // cross-wave sum of the snapshotted partials
        if (lane < 16) wred[q][lane] = sfin;
        __syncthreads();
        if (q == 0 && lane < 16) {
            float tot = wred[0][lane] + wred[1][lane] + wred[2][lane] + wred[3][lane];
            fcc_out[(wv << 4) + lane] = cfin + D9 * (float)len + __logf(tot);
        }
    } else {
        // ================= FAC (1 wave per batch, no barriers) =================
        const int b   = ((blockIdx.x - 8) << 2) + q;
        const int len = ilen[b];
        const int tl  = tlen[b];
        const float* xb = x + (size_t)b * Tt * Nn;

        int   tgi[4];
        float st[4], ntr[4], bt[4];
        #pragma unroll
        for (int r = 0; r < 4; ++r) {
            const int s = (lane << 2) + r;
            const int tgv = targets[b * Ss + s];
            const int pg  = (s == 0) ? tgv : targets[b * Ss + s - 1];
            tgi[r] = tgv;
            st[r]  = trans[tgv * Nn + tgv];
            ntr[r] = trans[tgv * Nn + pg];
            bt[r]  = (s == 0) ? xb[tgv] : NEGF;
        }
        // em ring depth 8; em[(k-1)&7] = x[k] for k=1..8 (constant indices)
        float em[8][4];
        #pragma unroll
        for (int k = 1; k <= 8; ++k) {
            int tt = k; if (tt > Tt - 1) tt = Tt - 1;
            const float* xrow = xb + (size_t)tt * Nn;
            em[(k - 1) & 7][0] = xrow[tgi[0]];
            em[(k - 1) & 7][1] = xrow[tgi[1]];
            em[(k - 1) & 7][2] = xrow[tgi[2]];
            em[(k - 1) & 7][3] = xrow[tgi[3]];
        }

        #pragma unroll
        for (int k = 1; k < 8; ++k) FAC_STEP(k, k)
        for (int tb = 8; tb < Tt; tb += 8) {
            #pragma unroll
            for (int k = 0; k < 8; ++k) FAC_STEP(tb + k, k)
        }

        #pragma unroll
        for (int r = 0; r < 4; ++r)
            if ((lane << 2) + r == tl - 1) fac_out[b] = bt[r];
    }
}

__global__ __launch_bounds__(128) void reduce_kernel(const float* __restrict__ fcc,
                                                     const float* __restrict__ fac,
                                                     float* __restrict__ out) {
    __shared__ float r2[2];
    int tid = threadIdx.x;
    float v = fcc[tid] - fac[tid];
    #pragma unroll
    for (int o = 32; o > 0; o >>= 1) v += __shfl_xor(v, o);
    if ((tid & 63) == 0) r2[tid >> 6] = v;
    __syncthreads();
    if (tid == 0) out[0] = (r2[0] + r2[1]) * (1.0f / Bb);
}

extern "C" void kernel_launch(void* const* d_in, const int* in_sizes, int n_in,
                              void* d_out, int out_size, void* d_ws, size_t ws_size,
                              hipStream_t stream) {
    const float* trans   = (const float*)d_in[0];
    const float* x       = (const float*)d_in[1];
    const int*   targets = (const int*)d_in[2];
    const int*   ilen    = (const int*)d_in[3];
    const int*   tlen    = (const int*)d_in[4];
    float* out = (float*)d_out;

    float* fcc = (float*)d_ws;                       // B floats
    float* fac = fcc + Bb;                           // B floats
    float* Wm  = (float*)((char*)d_ws + 2048);       // B*T*N floats (if it fits)

    const size_t wbytes = (size_t)Bb * Tt * Nn * sizeof(float);
    const bool pre = ws_size >= wbytes + 2048;

    if (pre) {
        exp_w_kernel<<<8192, 256, 0, stream>>>(x, Wm);
        asg_main<true><<<40, 256, 0, stream>>>(trans, x, Wm, targets, ilen, tlen, fcc, fac);
    } else {
        asg_main<false><<<40, 256, 0, stream>>>(trans, x, x, targets, ilen, tlen, fcc, fac);
    }
    reduce_kernel<<<1, 128, 0, stream>>>(fcc, fac, out);
}